// Round 7
// baseline (123.099 us; speedup 1.0000x reference)
//
#include <hip/hip_runtime.h>

// Bicubic 2x downsample, input (4,3,768,768) f32 -> res (4,3,384,384) +
// broadcast weight tensor (4,1,384,384,36).
//
// KEY FACT: scale = 0.5 exactly => u = 2j+1.5, left = 2j-1, off = 2.5-q
// EXACTLY in f32 for every position (clipping only touches indices).
// So the normalized 6-tap filter is a position-independent constant on both
// axes, taps are 6 CONSECUTIVE rows/cols (clamped at borders), and the
// entire 85 MB weight tensor is one repeating 36-float (144 B) pattern.
//
// R4 change: nontemporal stores via clang ext_vector_type (HIP float4 is a
// class type that __builtin_nontemporal_store rejects).
// R5-R7: identical resubmits — rounds 4-6 hit GPU-broker infra failures.

#define IHW 768
#define OHW 384
#define PP  6
#define NBC 12                      // 4*3 batch*channel planes
#define RES_N  (NBC * OHW * OHW)            // 1,769,472
#define KER_N  (4 * OHW * OHW * PP * PP)    // 21,233,664
#define KER_F4 (KER_N / 4)                  // 5,308,416

#define SX_N 96                     // 4-wide output patches per row
#define SY_N 192                    // 2-tall output patches per col
#define RES_THREADS (NBC * SX_N * SY_N)     // 221,184
#define RES_BLOCKS  (RES_THREADS / 256)     // 864
#define WMAT_THREADS 147456                 // 9 * 16384 -> stride % 9 == 0
#define WMAT_BLOCKS  (WMAT_THREADS / 256)   // 576

typedef float f32x4 __attribute__((ext_vector_type(4)));

__device__ __forceinline__ float cubic_w(float x) {
    float a  = fabsf(x);
    float a2 = a * a, a3 = a2 * a;
    float r1 = 1.5f * a3 - 2.5f * a2 + 1.0f;
    float r2 = -0.5f * a3 + 2.5f * a2 - 4.0f * a + 2.0f;
    return a <= 1.0f ? r1 : (a <= 2.0f ? r2 : 0.0f);
}

// Position-independent normalized 6-tap filter (same for rows and cols).
__device__ __forceinline__ void calc_wn(float wn[PP]) {
    float s = 0.0f;
    #pragma unroll
    for (int q = 0; q < PP; ++q) {
        wn[q] = cubic_w((2.5f - (float)q) * 0.5f);
        s += wn[q];
    }
    float inv = 1.0f / s;
    #pragma unroll
    for (int q = 0; q < PP; ++q) wn[q] *= inv;
}

__global__ __launch_bounds__(256) void bicubic_fused_kernel(
        const float* __restrict__ in, float* __restrict__ out) {
    float* res  = out;
    float* kout = out + RES_N;

    float wn[PP];
    calc_wn(wn);

    int blk = blockIdx.x;
    if (blk < RES_BLOCKS) {
        // ---- res: each thread computes a 4-wide x 2-tall output patch ----
        int g   = blk * 256 + threadIdx.x;          // < RES_THREADS exactly
        int sx  = g % SX_N;
        int t1  = g / SX_N;
        int sy  = t1 % SY_N;
        int bc  = t1 / SY_N;
        int j0  = 4 * sx;                           // output cols j0..j0+3
        int i0  = 2 * sy;                           // output rows i0..i0+1
        int col0 = 8 * sx - 4;                      // first loaded input col
        const float* base = in + (size_t)bc * (IHW * IHW);
        bool edge = (sx == 0) | (sx == SX_N - 1);

        float acc[2][4] = {{0.f,0.f,0.f,0.f},{0.f,0.f,0.f,0.f}};

        #pragma unroll
        for (int k = 0; k < 8; ++k) {
            int row = 4 * sy - 2 + k;
            row = min(max(row, 0), IHW - 1);        // clamp = reference clip
            const float* rp = base + (size_t)row * IHW;

            float v[16];
            if (edge) {
                #pragma unroll
                for (int m = 0; m < 16; ++m) {
                    int c = col0 + m;
                    c = min(max(c, 0), IHW - 1);
                    v[m] = rp[c];
                }
            } else {
                const f32x4* p4 = (const f32x4*)(rp + col0);  // 16B aligned
                f32x4 A = p4[0], B = p4[1], C = p4[2], D = p4[3];
                v[0]=A.x; v[1]=A.y; v[2]=A.z; v[3]=A.w;
                v[4]=B.x; v[5]=B.y; v[6]=B.z; v[7]=B.w;
                v[8]=C.x; v[9]=C.y; v[10]=C.z; v[11]=C.w;
                v[12]=D.x; v[13]=D.y; v[14]=D.z; v[15]=D.w;
            }

            #pragma unroll
            for (int c = 0; c < 4; ++c) {
                // horizontal 6-tap at output col j0+c: local cols 2c+2 .. 2c+7
                float h = wn[0] * v[2*c + 2];
                h = fmaf(wn[1], v[2*c + 3], h);
                h = fmaf(wn[2], v[2*c + 4], h);
                h = fmaf(wn[3], v[2*c + 5], h);
                h = fmaf(wn[4], v[2*c + 6], h);
                h = fmaf(wn[5], v[2*c + 7], h);
                // vertical: input row k feeds output o when p = k-2o in [0,5]
                #pragma unroll
                for (int o = 0; o < 2; ++o) {
                    int p = k - 2 * o;
                    if (p >= 0 && p < PP)
                        acc[o][c] = fmaf(wn[p], h, acc[o][c]);
                }
            }
        }

        #pragma unroll
        for (int o = 0; o < 2; ++o) {
            f32x4 r;
            r.x = acc[o][0]; r.y = acc[o][1]; r.z = acc[o][2]; r.w = acc[o][3];
            f32x4* dst = (f32x4*)(res + ((size_t)(bc * OHW + i0 + o) * OHW + j0));
            __builtin_nontemporal_store(r, dst);
        }
    } else {
        // ---- wmat: stream one repeating 9-float4 pattern over 85 MB ----
        int t = (blk - RES_BLOCKS) * 256 + threadIdx.x;   // < WMAT_THREADS
        int r = t % 9;            // fixed per thread since stride % 9 == 0
        f32x4 pat;
        // float4 #r of the 36-float pattern wn[p]*wn[q], kk = 4r+j, p=kk/6,q=kk%6
        switch (r) {
            case 0: pat = (f32x4){wn[0]*wn[0], wn[0]*wn[1], wn[0]*wn[2], wn[0]*wn[3]}; break;
            case 1: pat = (f32x4){wn[0]*wn[4], wn[0]*wn[5], wn[1]*wn[0], wn[1]*wn[1]}; break;
            case 2: pat = (f32x4){wn[1]*wn[2], wn[1]*wn[3], wn[1]*wn[4], wn[1]*wn[5]}; break;
            case 3: pat = (f32x4){wn[2]*wn[0], wn[2]*wn[1], wn[2]*wn[2], wn[2]*wn[3]}; break;
            case 4: pat = (f32x4){wn[2]*wn[4], wn[2]*wn[5], wn[3]*wn[0], wn[3]*wn[1]}; break;
            case 5: pat = (f32x4){wn[3]*wn[2], wn[3]*wn[3], wn[3]*wn[4], wn[3]*wn[5]}; break;
            case 6: pat = (f32x4){wn[4]*wn[0], wn[4]*wn[1], wn[4]*wn[2], wn[4]*wn[3]}; break;
            case 7: pat = (f32x4){wn[4]*wn[4], wn[4]*wn[5], wn[5]*wn[0], wn[5]*wn[1]}; break;
            default: pat = (f32x4){wn[5]*wn[2], wn[5]*wn[3], wn[5]*wn[4], wn[5]*wn[5]}; break;
        }
        f32x4* k4 = (f32x4*)kout;
        for (int f = t; f < KER_F4; f += WMAT_THREADS)    // 36 iters, coalesced
            __builtin_nontemporal_store(pat, k4 + f);
    }
}

extern "C" void kernel_launch(void* const* d_in, const int* in_sizes, int n_in,
                              void* d_out, int out_size, void* d_ws, size_t ws_size,
                              hipStream_t stream) {
    const float* input = (const float*)d_in[0];
    float* out = (float*)d_out;
    bicubic_fused_kernel<<<RES_BLOCKS + WMAT_BLOCKS, 256, 0, stream>>>(input, out);
}

// Round 8
// 119.467 us; speedup vs baseline: 1.0304x; 1.0304x over previous
//
#include <hip/hip_runtime.h>

// Bicubic 2x downsample, input (4,3,768,768) f32 -> res (4,3,384,384) +
// broadcast weight tensor (4,1,384,384,36).
//
// KEY FACT: scale = 0.5 exactly => u = 2j+1.5, left = 2j-1, off = 2.5-q
// EXACTLY in f32 for every position (clipping only touches indices).
// So the normalized 6-tap filter is a position-independent constant on both
// axes, taps are 6 CONSECUTIVE rows/cols (clamped at borders), and the
// entire 85 MB weight tensor is one repeating 36-float (144 B) pattern.
//
// R8: FINAL — revert R4's nontemporal stores (A/B: 119.2 -> 123.1 us, a
// ~3% regression; plain cached stores measured best). Structure = R2:
// one fused launch, res patch kernel + wmat pattern stream.

#define IHW 768
#define OHW 384
#define PP  6
#define NBC 12                      // 4*3 batch*channel planes
#define RES_N  (NBC * OHW * OHW)            // 1,769,472
#define KER_N  (4 * OHW * OHW * PP * PP)    // 21,233,664
#define KER_F4 (KER_N / 4)                  // 5,308,416

#define SX_N 96                     // 4-wide output patches per row
#define SY_N 192                    // 2-tall output patches per col
#define RES_THREADS (NBC * SX_N * SY_N)     // 221,184
#define RES_BLOCKS  (RES_THREADS / 256)     // 864
#define WMAT_THREADS 147456                 // 9 * 16384 -> stride % 9 == 0
#define WMAT_BLOCKS  (WMAT_THREADS / 256)   // 576

typedef float f32x4 __attribute__((ext_vector_type(4)));

__device__ __forceinline__ float cubic_w(float x) {
    float a  = fabsf(x);
    float a2 = a * a, a3 = a2 * a;
    float r1 = 1.5f * a3 - 2.5f * a2 + 1.0f;
    float r2 = -0.5f * a3 + 2.5f * a2 - 4.0f * a + 2.0f;
    return a <= 1.0f ? r1 : (a <= 2.0f ? r2 : 0.0f);
}

// Position-independent normalized 6-tap filter (same for rows and cols).
__device__ __forceinline__ void calc_wn(float wn[PP]) {
    float s = 0.0f;
    #pragma unroll
    for (int q = 0; q < PP; ++q) {
        wn[q] = cubic_w((2.5f - (float)q) * 0.5f);
        s += wn[q];
    }
    float inv = 1.0f / s;
    #pragma unroll
    for (int q = 0; q < PP; ++q) wn[q] *= inv;
}

__global__ __launch_bounds__(256) void bicubic_fused_kernel(
        const float* __restrict__ in, float* __restrict__ out) {
    float* res  = out;
    float* kout = out + RES_N;

    float wn[PP];
    calc_wn(wn);

    int blk = blockIdx.x;
    if (blk < RES_BLOCKS) {
        // ---- res: each thread computes a 4-wide x 2-tall output patch ----
        int g   = blk * 256 + threadIdx.x;          // < RES_THREADS exactly
        int sx  = g % SX_N;
        int t1  = g / SX_N;
        int sy  = t1 % SY_N;
        int bc  = t1 / SY_N;
        int j0  = 4 * sx;                           // output cols j0..j0+3
        int i0  = 2 * sy;                           // output rows i0..i0+1
        int col0 = 8 * sx - 4;                      // first loaded input col
        const float* base = in + (size_t)bc * (IHW * IHW);
        bool edge = (sx == 0) | (sx == SX_N - 1);

        float acc[2][4] = {{0.f,0.f,0.f,0.f},{0.f,0.f,0.f,0.f}};

        #pragma unroll
        for (int k = 0; k < 8; ++k) {
            int row = 4 * sy - 2 + k;
            row = min(max(row, 0), IHW - 1);        // clamp = reference clip
            const float* rp = base + (size_t)row * IHW;

            float v[16];
            if (edge) {
                #pragma unroll
                for (int m = 0; m < 16; ++m) {
                    int c = col0 + m;
                    c = min(max(c, 0), IHW - 1);
                    v[m] = rp[c];
                }
            } else {
                const f32x4* p4 = (const f32x4*)(rp + col0);  // 16B aligned
                f32x4 A = p4[0], B = p4[1], C = p4[2], D = p4[3];
                v[0]=A.x; v[1]=A.y; v[2]=A.z; v[3]=A.w;
                v[4]=B.x; v[5]=B.y; v[6]=B.z; v[7]=B.w;
                v[8]=C.x; v[9]=C.y; v[10]=C.z; v[11]=C.w;
                v[12]=D.x; v[13]=D.y; v[14]=D.z; v[15]=D.w;
            }

            #pragma unroll
            for (int c = 0; c < 4; ++c) {
                // horizontal 6-tap at output col j0+c: local cols 2c+2 .. 2c+7
                float h = wn[0] * v[2*c + 2];
                h = fmaf(wn[1], v[2*c + 3], h);
                h = fmaf(wn[2], v[2*c + 4], h);
                h = fmaf(wn[3], v[2*c + 5], h);
                h = fmaf(wn[4], v[2*c + 6], h);
                h = fmaf(wn[5], v[2*c + 7], h);
                // vertical: input row k feeds output o when p = k-2o in [0,5]
                #pragma unroll
                for (int o = 0; o < 2; ++o) {
                    int p = k - 2 * o;
                    if (p >= 0 && p < PP)
                        acc[o][c] = fmaf(wn[p], h, acc[o][c]);
                }
            }
        }

        #pragma unroll
        for (int o = 0; o < 2; ++o) {
            f32x4 r;
            r.x = acc[o][0]; r.y = acc[o][1]; r.z = acc[o][2]; r.w = acc[o][3];
            *(f32x4*)(res + ((size_t)(bc * OHW + i0 + o) * OHW + j0)) = r;
        }
    } else {
        // ---- wmat: stream one repeating 9-float4 pattern over 85 MB ----
        int t = (blk - RES_BLOCKS) * 256 + threadIdx.x;   // < WMAT_THREADS
        int r = t % 9;            // fixed per thread since stride % 9 == 0
        f32x4 pat;
        // float4 #r of the 36-float pattern wn[p]*wn[q], kk = 4r+j, p=kk/6,q=kk%6
        switch (r) {
            case 0: pat = (f32x4){wn[0]*wn[0], wn[0]*wn[1], wn[0]*wn[2], wn[0]*wn[3]}; break;
            case 1: pat = (f32x4){wn[0]*wn[4], wn[0]*wn[5], wn[1]*wn[0], wn[1]*wn[1]}; break;
            case 2: pat = (f32x4){wn[1]*wn[2], wn[1]*wn[3], wn[1]*wn[4], wn[1]*wn[5]}; break;
            case 3: pat = (f32x4){wn[2]*wn[0], wn[2]*wn[1], wn[2]*wn[2], wn[2]*wn[3]}; break;
            case 4: pat = (f32x4){wn[2]*wn[4], wn[2]*wn[5], wn[3]*wn[0], wn[3]*wn[1]}; break;
            case 5: pat = (f32x4){wn[3]*wn[2], wn[3]*wn[3], wn[3]*wn[4], wn[3]*wn[5]}; break;
            case 6: pat = (f32x4){wn[4]*wn[0], wn[4]*wn[1], wn[4]*wn[2], wn[4]*wn[3]}; break;
            case 7: pat = (f32x4){wn[4]*wn[4], wn[4]*wn[5], wn[5]*wn[0], wn[5]*wn[1]}; break;
            default: pat = (f32x4){wn[5]*wn[2], wn[5]*wn[3], wn[5]*wn[4], wn[5]*wn[5]}; break;
        }
        f32x4* k4 = (f32x4*)kout;
        for (int f = t; f < KER_F4; f += WMAT_THREADS)    // 36 iters, coalesced
            k4[f] = pat;
    }
}

extern "C" void kernel_launch(void* const* d_in, const int* in_sizes, int n_in,
                              void* d_out, int out_size, void* d_ws, size_t ws_size,
                              hipStream_t stream) {
    const float* input = (const float*)d_in[0];
    float* out = (float*)d_out;
    bicubic_fused_kernel<<<RES_BLOCKS + WMAT_BLOCKS, 256, 0, stream>>>(input, out);
}